// Round 1
// baseline (129.914 us; speedup 1.0000x reference)
//
#include <hip/hip_runtime.h>

#define NN 2048
#define ROWS 32
#define TILE 256

__global__ void ktau_init_ws(int* __restrict__ ws) {
    int t = threadIdx.x;
    if (t < 2 * ROWS) ws[t] = 0;
}

// blockIdx.x = row*64 + ti*8 + tj ; tiles with tj < ti exit immediately.
// Thread handles i = ti*256 + tid; loops j over tile tj (block-uniform -> s_load).
__global__ __launch_bounds__(256) void ktau_count(const float* __restrict__ pred,
                                                  const float* __restrict__ target,
                                                  int* __restrict__ ws) {
    int b   = blockIdx.x;
    int row = b >> 6;
    int t6  = b & 63;
    int ti  = t6 >> 3;
    int tj  = t6 & 7;
    if (tj < ti) return;

    const float* __restrict__ prow = pred   + row * NN;
    const float* __restrict__ qrow = target + row * NN;

    int i    = ti * TILE + (int)threadIdx.x;
    float pi = prow[i];
    float qi = qrow[i];

    int conc = 0, disc = 0;
    int jbase = tj * TILE;

    if (ti == tj) {
        // diagonal tile: only j > i pairs
        #pragma unroll 8
        for (int jj = 0; jj < TILE; ++jj) {
            int j    = jbase + jj;           // uniform
            float pj = prow[j];              // scalar load
            float qj = qrow[j];
            if (j > i) {
                // stable argsort: pj==pi with j>i means i sorts first => j is "later"
                bool jl = (pj >= pi);
                int g = (qj > qi);
                int l = (qj < qi);
                conc += jl ? g : l;
                disc += jl ? l : g;
            }
        }
    } else {
        #pragma unroll 8
        for (int jj = 0; jj < TILE; ++jj) {
            int j    = jbase + jj;
            float pj = prow[j];
            float qj = qrow[j];
            bool jl = (pj >= pi);
            int g = (qj > qi);
            int l = (qj < qi);
            conc += jl ? g : l;
            disc += jl ? l : g;
        }
    }

    // wave-64 shuffle reduction
    #pragma unroll
    for (int off = 32; off > 0; off >>= 1) {
        conc += __shfl_down(conc, off, 64);
        disc += __shfl_down(disc, off, 64);
    }
    if ((threadIdx.x & 63) == 0) {
        atomicAdd(&ws[row * 2 + 0], conc);
        atomicAdd(&ws[row * 2 + 1], disc);
    }
}

__global__ void ktau_final(const int* __restrict__ ws, float* __restrict__ out) {
    int t = threadIdx.x;   // 64 threads
    float loss = 0.0f;
    if (t < ROWS) {
        float c = (float)ws[t * 2 + 0];
        float d = (float)ws[t * 2 + 1];
        float tau = (c - d) / (c + d);
        loss = 1.0f - tau;
    }
    #pragma unroll
    for (int off = 32; off > 0; off >>= 1) loss += __shfl_down(loss, off, 64);
    if (t == 0) out[0] = loss / (float)ROWS;
}

extern "C" void kernel_launch(void* const* d_in, const int* in_sizes, int n_in,
                              void* d_out, int out_size, void* d_ws, size_t ws_size,
                              hipStream_t stream) {
    const float* pred   = (const float*)d_in[0];
    const float* target = (const float*)d_in[1];
    float* out = (float*)d_out;
    int* ws    = (int*)d_ws;

    ktau_init_ws<<<1, 64, 0, stream>>>(ws);
    ktau_count<<<ROWS * 64, 256, 0, stream>>>(pred, target, ws);
    ktau_final<<<1, 64, 0, stream>>>(ws, out);
}

// Round 2
// 100.121 us; speedup vs baseline: 1.2976x; 1.2976x over previous
//
#include <hip/hip_runtime.h>

#define NN 2048
#define ROWS 32
#define TJ 128
#define JT (NN / TJ)          // 16 j-tiles per row
#define IB 8                  // i-values per thread (in registers)
#define THREADS 256           // 256 * IB = 2048 = full row of i per block
#define GRID (ROWS * JT)      // 512 blocks, uniform work

static_assert(JT == 16, "row extraction uses >>4");
static_assert(THREADS * IB == NN, "block must cover full i range");

// ws layout: ws[0..31] = per-row float S (sum over ordered pairs of +/-1),
//            ((int*)ws)[32] = done-counter
__global__ void ktau_init(float* __restrict__ ws) {
    int t = threadIdx.x;
    if (t < ROWS) ws[t] = 0.0f;
    if (t == 0) ((int*)ws)[ROWS] = 0;
}

__global__ __launch_bounds__(THREADS) void ktau_count(const float* __restrict__ pred,
                                                      const float* __restrict__ target,
                                                      float* __restrict__ ws,
                                                      float* __restrict__ out) {
    __shared__ float2 jtile[TJ];

    const int blk = blockIdx.x;
    const int row = blk >> 4;            // / JT
    const int jt  = blk & (JT - 1);
    const float* __restrict__ prow = pred   + row * NN;
    const float* __restrict__ qrow = target + row * NN;
    const int tid = threadIdx.x;

    // stage j-tile (pred,target interleaved -> one ds_read_b64 per j)
    if (tid < TJ) {
        int j = jt * TJ + tid;
        jtile[tid] = make_float2(prow[j], qrow[j]);
    }

    // register-block 8 consecutive i values per thread (float4 loads, 32B aligned)
    float pi[IB], qi[IB];
    {
        const float4* p4 = (const float4*)(prow + tid * IB);
        const float4* q4 = (const float4*)(qrow + tid * IB);
        float4 a0 = p4[0], a1 = p4[1];
        float4 b0 = q4[0], b1 = q4[1];
        pi[0]=a0.x; pi[1]=a0.y; pi[2]=a0.z; pi[3]=a0.w;
        pi[4]=a1.x; pi[5]=a1.y; pi[6]=a1.z; pi[7]=a1.w;
        qi[0]=b0.x; qi[1]=b0.y; qi[2]=b0.z; qi[3]=b0.w;
        qi[4]=b1.x; qi[5]=b1.y; qi[6]=b1.z; qi[7]=b1.w;
    }
    __syncthreads();

    // S += (sign(pj-pi) == sign(qj-qi)) ? +1 : -1 over all ordered pairs
    // (tie-free data; diagonal contributes +1 per i, corrected in finalize)
    float S = 0.0f;
    #pragma unroll 4
    for (int jj = 0; jj < TJ; ++jj) {
        float2 pq = jtile[jj];
        #pragma unroll
        for (int k = 0; k < IB; ++k) {
            bool bp = pi[k] < pq.x;
            bool bq = qi[k] < pq.y;
            S += (bp == bq) ? 1.0f : -1.0f;
        }
    }

    // wave-64 reduce, one float atomic per wave (integer-valued -> exact)
    #pragma unroll
    for (int off = 32; off > 0; off >>= 1)
        S += __shfl_down(S, off, 64);
    if ((tid & 63) == 0)
        atomicAdd(&ws[row], S);

    __syncthreads();
    if (tid == 0) {
        __threadfence();
        int old = atomicAdd((int*)ws + ROWS, 1);
        if (old == GRID - 1) {
            // last block finalizes: tau_r = D_r / T, D_r = (S_r - N)/2
            const float T = (float)(((long long)NN * (NN - 1)) / 2);
            float acc = 0.0f;
            for (int r = 0; r < ROWS; ++r) {
                float Sr = atomicAdd(&ws[r], 0.0f);   // coherent read-modify-write
                float Dr = (Sr - (float)NN) * 0.5f;
                acc += 1.0f - Dr / T;
            }
            out[0] = acc / (float)ROWS;
        }
    }
}

extern "C" void kernel_launch(void* const* d_in, const int* in_sizes, int n_in,
                              void* d_out, int out_size, void* d_ws, size_t ws_size,
                              hipStream_t stream) {
    const float* pred   = (const float*)d_in[0];
    const float* target = (const float*)d_in[1];
    float* out = (float*)d_out;
    float* ws  = (float*)d_ws;

    ktau_init<<<1, 64, 0, stream>>>(ws);
    ktau_count<<<GRID, THREADS, 0, stream>>>(pred, target, ws, out);
}